// Round 1
// baseline (26.975 us; speedup 1.0000x reference)
//
#include <hip/hip_runtime.h>

// Problem constants (fixed by the reference file).
#define PPOOL 7
#define HH 256
#define WW 256
#define CC 512

// One block per (roi, py, px) output cell. 128 threads x float4 = 512 channels.
__global__ __launch_bounds__(128) void roi_pool_kernel(
    const float* __restrict__ img,   // (H, W, C)
    const int*   __restrict__ rois,  // (R, 4): x, y, w, h
    float*       __restrict__ out)   // (R, P, P, C)
{
    const int bid = blockIdx.x;
    const int px  = bid % PPOOL;
    const int py  = (bid / PPOOL) % PPOOL;
    const int r   = bid / (PPOOL * PPOOL);

    // ROI box (x, y, w, h) — one 16B broadcast load.
    const int4 roi = reinterpret_cast<const int4*>(rois)[r];
    const float wf = (float)roi.z;
    const float hf = (float)roi.w;

    // Source coords with half-pixel centers, clipped — matches reference f32 math.
    float sy = ((float)py + 0.5f) * hf / (float)PPOOL - 0.5f;
    sy = fminf(fmaxf(sy, 0.0f), hf - 1.0f);
    float sx = ((float)px + 0.5f) * wf / (float)PPOOL - 0.5f;
    sx = fminf(fmaxf(sx, 0.0f), wf - 1.0f);

    const int y0 = (int)floorf(sy);
    const int x0 = (int)floorf(sx);
    const int y1 = min(y0 + 1, roi.w - 1);
    const int x1 = min(x0 + 1, roi.z - 1);
    const float wy = sy - (float)y0;
    const float wx = sx - (float)x0;
    const float owy = 1.0f - wy;
    const float owx = 1.0f - wx;

    // Absolute pixel coords in the full feature map.
    const int y0a = y0 + roi.y, y1a = y1 + roi.y;
    const int x0a = x0 + roi.x, x1a = x1 + roi.x;

    const int c = threadIdx.x * 4;

    const float4 v00 = *reinterpret_cast<const float4*>(
        img + (size_t)(y0a * WW + x0a) * CC + c);
    const float4 v01 = *reinterpret_cast<const float4*>(
        img + (size_t)(y0a * WW + x1a) * CC + c);
    const float4 v10 = *reinterpret_cast<const float4*>(
        img + (size_t)(y1a * WW + x0a) * CC + c);
    const float4 v11 = *reinterpret_cast<const float4*>(
        img + (size_t)(y1a * WW + x1a) * CC + c);

    float4 o;
    {
        const float t0 = v00.x * owx + v01.x * wx;
        const float b0 = v10.x * owx + v11.x * wx;
        o.x = t0 * owy + b0 * wy;
        const float t1 = v00.y * owx + v01.y * wx;
        const float b1 = v10.y * owx + v11.y * wx;
        o.y = t1 * owy + b1 * wy;
        const float t2 = v00.z * owx + v01.z * wx;
        const float b2 = v10.z * owx + v11.z * wx;
        o.z = t2 * owy + b2 * wy;
        const float t3 = v00.w * owx + v01.w * wx;
        const float b3 = v10.w * owx + v11.w * wx;
        o.w = t3 * owy + b3 * wy;
    }

    *reinterpret_cast<float4*>(out + (size_t)bid * CC + c) = o;
}

extern "C" void kernel_launch(void* const* d_in, const int* in_sizes, int n_in,
                              void* d_out, int out_size, void* d_ws, size_t ws_size,
                              hipStream_t stream) {
    const float* img  = (const float*)d_in[0];
    const int*   rois = (const int*)d_in[1];
    float*       out  = (float*)d_out;

    const int R = in_sizes[1] / 4;          // 300 ROIs
    const int nblocks = R * PPOOL * PPOOL;  // one block per output cell

    roi_pool_kernel<<<nblocks, 128, 0, stream>>>(img, rois, out);
}

// Round 3
// 26.426 us; speedup vs baseline: 1.0208x; 1.0208x over previous
//
#include <hip/hip_runtime.h>

// Problem constants (fixed by the reference file).
#define PPOOL 7
#define HH 256
#define WW 256
#define CC 512
#define NCELL 4   // output cells per block (MLP batching)

typedef float floatx4 __attribute__((ext_vector_type(4)));  // native vec for nontemporal

// Each block processes NCELL consecutive (roi, py, px) output cells.
// 128 threads x float4 = 512 channels per cell.
// Phase 1: issue all NCELL*4 gathers. Phase 2: lerp + nontemporal store.
__global__ __launch_bounds__(128) void roi_pool_kernel(
    const float* __restrict__ img,   // (H, W, C)
    const int*   __restrict__ rois,  // (R, 4): x, y, w, h
    float*       __restrict__ out,   // (R, P, P, C)
    int ncells)
{
    const int c    = threadIdx.x * 4;
    const int base = blockIdx.x * NCELL;

    floatx4 v[NCELL][4];
    float   wxk[NCELL], wyk[NCELL];

    // ---- Phase 1: coords + issue all gathers ----
#pragma unroll
    for (int k = 0; k < NCELL; ++k) {
        const int cell = base + k;
        if (cell >= ncells) continue;

        const int px = cell % PPOOL;
        const int py = (cell / PPOOL) % PPOOL;
        const int r  = cell / (PPOOL * PPOOL);

        const int4 roi = reinterpret_cast<const int4*>(rois)[r];
        const float wf = (float)roi.z;
        const float hf = (float)roi.w;

        float sy = ((float)py + 0.5f) * hf / (float)PPOOL - 0.5f;
        sy = fminf(fmaxf(sy, 0.0f), hf - 1.0f);
        float sx = ((float)px + 0.5f) * wf / (float)PPOOL - 0.5f;
        sx = fminf(fmaxf(sx, 0.0f), wf - 1.0f);

        const int y0 = (int)floorf(sy);
        const int x0 = (int)floorf(sx);
        const int y1 = min(y0 + 1, roi.w - 1);
        const int x1 = min(x0 + 1, roi.z - 1);
        wyk[k] = sy - (float)y0;
        wxk[k] = sx - (float)x0;

        const int y0a = y0 + roi.y, y1a = y1 + roi.y;
        const int x0a = x0 + roi.x, x1a = x1 + roi.x;

        v[k][0] = *reinterpret_cast<const floatx4*>(
            img + (size_t)(y0a * WW + x0a) * CC + c);
        v[k][1] = *reinterpret_cast<const floatx4*>(
            img + (size_t)(y0a * WW + x1a) * CC + c);
        v[k][2] = *reinterpret_cast<const floatx4*>(
            img + (size_t)(y1a * WW + x0a) * CC + c);
        v[k][3] = *reinterpret_cast<const floatx4*>(
            img + (size_t)(y1a * WW + x1a) * CC + c);
    }

    // ---- Phase 2: lerp + nontemporal store ----
#pragma unroll
    for (int k = 0; k < NCELL; ++k) {
        const int cell = base + k;
        if (cell >= ncells) continue;

        const float wx = wxk[k], wy = wyk[k];
        const float owx = 1.0f - wx, owy = 1.0f - wy;

        floatx4 top = v[k][0] * owx + v[k][1] * wx;
        floatx4 bot = v[k][2] * owx + v[k][3] * wx;
        floatx4 o   = top * owy + bot * wy;

        __builtin_nontemporal_store(
            o, reinterpret_cast<floatx4*>(out + (size_t)cell * CC + c));
    }
}

extern "C" void kernel_launch(void* const* d_in, const int* in_sizes, int n_in,
                              void* d_out, int out_size, void* d_ws, size_t ws_size,
                              hipStream_t stream) {
    const float* img  = (const float*)d_in[0];
    const int*   rois = (const int*)d_in[1];
    float*       out  = (float*)d_out;

    const int R      = in_sizes[1] / 4;       // 300 ROIs
    const int ncells = R * PPOOL * PPOOL;     // 14700 output cells
    const int nblk   = (ncells + NCELL - 1) / NCELL;

    roi_pool_kernel<<<nblk, 128, 0, stream>>>(img, rois, out, ncells);
}

// Round 4
// 25.850 us; speedup vs baseline: 1.0435x; 1.0223x over previous
//
#include <hip/hip_runtime.h>

// Problem constants (fixed by the reference file).
#define PPOOL 7
#define HH 256
#define WW 256
#define CC 512
#define NCELL 4    // output cells per block
#define NXCD 8     // MI355X XCD count

typedef float floatx4 __attribute__((ext_vector_type(4)));

// Each block processes NCELL consecutive (roi, py, px) output cells.
// 128 threads x float4 = 512 channels per cell.
// blockIdx is XCD-swizzled (bijective chunked map, m204) so consecutive
// cells — which share bilinear source pixels — land on the same XCD's L2.
__global__ __launch_bounds__(128) void roi_pool_kernel(
    const float* __restrict__ img,   // (H, W, C)
    const int*   __restrict__ rois,  // (R, 4): x, y, w, h
    float*       __restrict__ out,   // (R, P, P, C)
    int ncells, int nblk)
{
    // --- bijective XCD-chunked swizzle: hardware round-robins blockIdx.x
    // across XCDs; remap so XCD k gets a contiguous chunk of cell-space. ---
    const int q = nblk / NXCD, rres = nblk % NXCD;
    const int xcd = blockIdx.x % NXCD;
    const int idx = blockIdx.x / NXCD;
    const int bid = (xcd < rres ? xcd * (q + 1) : rres * (q + 1) + (xcd - rres) * q) + idx;

    const int c    = threadIdx.x * 4;
    const int base = bid * NCELL;

    floatx4 v[NCELL][4];
    float   wxk[NCELL], wyk[NCELL];

    // ---- Phase 1: coords + issue all gathers ----
#pragma unroll
    for (int k = 0; k < NCELL; ++k) {
        const int cell = base + k;
        if (cell >= ncells) continue;

        const int px = cell % PPOOL;
        const int py = (cell / PPOOL) % PPOOL;
        const int r  = cell / (PPOOL * PPOOL);

        const int4 roi = reinterpret_cast<const int4*>(rois)[r];
        const float wf = (float)roi.z;
        const float hf = (float)roi.w;

        float sy = ((float)py + 0.5f) * hf / (float)PPOOL - 0.5f;
        sy = fminf(fmaxf(sy, 0.0f), hf - 1.0f);
        float sx = ((float)px + 0.5f) * wf / (float)PPOOL - 0.5f;
        sx = fminf(fmaxf(sx, 0.0f), wf - 1.0f);

        const int y0 = (int)floorf(sy);
        const int x0 = (int)floorf(sx);
        const int y1 = min(y0 + 1, roi.w - 1);
        const int x1 = min(x0 + 1, roi.z - 1);
        wyk[k] = sy - (float)y0;
        wxk[k] = sx - (float)x0;

        const int y0a = y0 + roi.y, y1a = y1 + roi.y;
        const int x0a = x0 + roi.x, x1a = x1 + roi.x;

        v[k][0] = *reinterpret_cast<const floatx4*>(
            img + (size_t)(y0a * WW + x0a) * CC + c);
        v[k][1] = *reinterpret_cast<const floatx4*>(
            img + (size_t)(y0a * WW + x1a) * CC + c);
        v[k][2] = *reinterpret_cast<const floatx4*>(
            img + (size_t)(y1a * WW + x0a) * CC + c);
        v[k][3] = *reinterpret_cast<const floatx4*>(
            img + (size_t)(y1a * WW + x1a) * CC + c);
    }

    // ---- Phase 2: lerp + nontemporal store ----
#pragma unroll
    for (int k = 0; k < NCELL; ++k) {
        const int cell = base + k;
        if (cell >= ncells) continue;

        const float wx = wxk[k], wy = wyk[k];
        const float owx = 1.0f - wx, owy = 1.0f - wy;

        floatx4 top = v[k][0] * owx + v[k][1] * wx;
        floatx4 bot = v[k][2] * owx + v[k][3] * wx;
        floatx4 o   = top * owy + bot * wy;

        __builtin_nontemporal_store(
            o, reinterpret_cast<floatx4*>(out + (size_t)cell * CC + c));
    }
}

extern "C" void kernel_launch(void* const* d_in, const int* in_sizes, int n_in,
                              void* d_out, int out_size, void* d_ws, size_t ws_size,
                              hipStream_t stream) {
    const float* img  = (const float*)d_in[0];
    const int*   rois = (const int*)d_in[1];
    float*       out  = (float*)d_out;

    const int R      = in_sizes[1] / 4;       // 300 ROIs
    const int ncells = R * PPOOL * PPOOL;     // 14700 output cells
    const int nblk   = (ncells + NCELL - 1) / NCELL;

    roi_pool_kernel<<<nblk, 128, 0, stream>>>(img, rois, out, ncells, nblk);
}